// Round 2
// baseline (587.445 us; speedup 1.0000x reference)
//
#include <hip/hip_runtime.h>

#define NSEQ   64
#define NHEAD  32
#define KVH    8
#define HS     128
#define BS     16
#define MBPS   64
#define PARTS  8
#define PSIZE  128   // tokens per partition (8 pages)
#define QPKV   4
#define SCALE_F 0.08838834764831845f

#define O_PART_ELEMS (NSEQ*KVH*PARTS*QPKV*HS)
#define ML_ELEMS     (NSEQ*KVH*PARTS*QPKV)

// One WG per (seq, kv_head, partition). Wave w handles query head g=w of the
// GQA group -> everything (scores, softmax, PV) is wave-private: no barriers.
__launch_bounds__(256, 4)
__global__ void pa_part(const float* __restrict__ q,
                        const float* __restrict__ kc,
                        const float* __restrict__ vc,
                        const int*   __restrict__ bt,
                        const int*   __restrict__ cl,
                        float*       __restrict__ o_part,
                        float*       __restrict__ m_part,
                        float*       __restrict__ l_part)
{
    const int bx   = blockIdx.x;
    const int part = bx & (PARTS - 1);
    const int kvh  = (bx >> 3) & (KVH - 1);
    const int seq  = bx >> 6;
    const int ctx  = cl[seq];
    const int tok0 = part * PSIZE;
    if (tok0 >= ctx) return;                    // empty partition
    const int ntok = min(PSIZE, ctx - tok0);
    const int nbl  = (ntok + BS - 1) / BS;      // pages in this partition (<=8)

    const int w    = threadIdx.x >> 6;          // query head within GQA group
    const int lane = threadIdx.x & 63;
    const int tok  = lane & 15;                 // token within page
    const int dq   = lane >> 4;                 // dim quarter: dims [dq*32, +32)

    __shared__ float sc[QPKV][PSIZE];           // wave-private rows

    // Q: 32 dims for (head w, quarter dq), held in registers
    const float* qp = q + ((size_t)seq * NHEAD + kvh * QPKV + w) * HS + dq * 32;
    float4 qv[8];
#pragma unroll
    for (int k = 0; k < 8; ++k) qv[k] = ((const float4*)qp)[k];

    const int* btrow = bt + seq * MBPS + part * (PSIZE / BS);

    // ---- Pass 1: scores ----
    // K layout (blk,kvh): [dpart(16)][tok(16)][8] floats, 8 KB contiguous.
    // Lane reads dims dq*32..+31 of its token: 4 x float8, each 16-lane group
    // covers a contiguous 512 B segment. Coalesced.
    for (int b = 0; b < nbl; ++b) {
        const int blk = btrow[b];
        const float* kb = kc + ((size_t)blk * KVH + kvh) * (HS * BS);
        float s = 0.f;
#pragma unroll
        for (int k = 0; k < 4; ++k) {
            const float4* kp = (const float4*)(kb + (dq * 4 + k) * (BS * 8) + tok * 8);
            const float4 k0 = kp[0], k1 = kp[1];
            const float4 q0 = qv[2 * k], q1 = qv[2 * k + 1];
            s += q0.x*k0.x + q0.y*k0.y + q0.z*k0.z + q0.w*k0.w
               + q1.x*k1.x + q1.y*k1.y + q1.z*k1.z + q1.w*k1.w;
        }
        s += __shfl_xor(s, 16);                 // reduce over the 4 dim-quarters
        s += __shfl_xor(s, 32);
        if (lane < 16)
            sc[w][b * BS + tok] = s * SCALE_F;
    }

    // ---- wave-private softmax over sc[w][0..ntok) ----
    float m = -1e30f;
    for (int i = lane; i < ntok; i += 64) m = fmaxf(m, sc[w][i]);
#pragma unroll
    for (int off = 32; off >= 1; off >>= 1) m = fmaxf(m, __shfl_xor(m, off));
    float lsum = 0.f;
    const int lim = nbl * BS;
    for (int i = lane; i < lim; i += 64) {
        float v = (i < ntok) ? __expf(sc[w][i] - m) : 0.f;
        sc[w][i] = v;                           // unnormalized probs, tail zeroed
        lsum += v;
    }
#pragma unroll
    for (int off = 32; off >= 1; off >>= 1) lsum += __shfl_xor(lsum, off);

    // ---- Pass 2: O_part = P . V ----
    // V layout (blk,kvh): [d(128)][tok(16)], 8 KB contiguous. Lane reads the
    // contiguous 128 B strip for dims {2*lane, 2*lane+1}. Perfectly coalesced.
    float acc0 = 0.f, acc1 = 0.f;
    for (int b = 0; b < nbl; ++b) {
        const int blk = btrow[b];
        const float4* vp = (const float4*)(vc + ((size_t)blk * KVH + kvh) * (HS * BS)
                                              + (size_t)lane * 32);
        const float4 p0 = *(const float4*)&sc[w][b * BS + 0];
        const float4 p1 = *(const float4*)&sc[w][b * BS + 4];
        const float4 p2 = *(const float4*)&sc[w][b * BS + 8];
        const float4 p3 = *(const float4*)&sc[w][b * BS + 12];
        const float4 a0 = vp[0], a1 = vp[1], a2 = vp[2], a3 = vp[3];
        const float4 b0 = vp[4], b1 = vp[5], b2 = vp[6], b3 = vp[7];
        acc0 += p0.x*a0.x + p0.y*a0.y + p0.z*a0.z + p0.w*a0.w
              + p1.x*a1.x + p1.y*a1.y + p1.z*a1.z + p1.w*a1.w
              + p2.x*a2.x + p2.y*a2.y + p2.z*a2.z + p2.w*a2.w
              + p3.x*a3.x + p3.y*a3.y + p3.z*a3.z + p3.w*a3.w;
        acc1 += p0.x*b0.x + p0.y*b0.y + p0.z*b0.z + p0.w*b0.w
              + p1.x*b1.x + p1.y*b1.y + p1.z*b1.z + p1.w*b1.w
              + p2.x*b2.x + p2.y*b2.y + p2.z*b2.z + p2.w*b2.w
              + p3.x*b3.x + p3.y*b3.y + p3.z*b3.z + p3.w*b3.w;
    }

    const int    idx   = ((seq * KVH + kvh) * PARTS + part) * QPKV + w;
    const size_t obase = (size_t)idx * HS;
    ((float2*)(o_part + obase))[lane] = make_float2(acc0, acc1);
    if (lane == 0) { m_part[idx] = m; l_part[idx] = lsum; }
}

// One WG (128 threads) per (seq, head): merge <=8 partitions.
__launch_bounds__(128)
__global__ void pa_combine(const float* __restrict__ o_part,
                           const float* __restrict__ m_part,
                           const float* __restrict__ l_part,
                           const int*   __restrict__ cl,
                           float*       __restrict__ out)
{
    const int h   = blockIdx.x & (NHEAD - 1);
    const int seq = blockIdx.x >> 5;
    const int kvh = h >> 2;
    const int g   = h & 3;
    const int d   = threadIdx.x;
    const int ctx = cl[seq];
    const int np  = (ctx + PSIZE - 1) / PSIZE;

    const int base = (seq * KVH + kvh) * PARTS * QPKV + g;
    float M = -1e30f;
    for (int p = 0; p < np; ++p)
        M = fmaxf(M, m_part[base + p * QPKV]);
    float L = 0.f, acc = 0.f;
    for (int p = 0; p < np; ++p) {
        const float w  = __expf(m_part[base + p * QPKV] - M);
        L   += l_part[base + p * QPKV] * w;
        acc += w * o_part[(size_t)(base + p * QPKV) * HS + d];
    }
    out[((size_t)seq * NHEAD + h) * HS + d] = acc / L;
}

extern "C" void kernel_launch(void* const* d_in, const int* in_sizes, int n_in,
                              void* d_out, int out_size, void* d_ws, size_t ws_size,
                              hipStream_t stream) {
    const float* query        = (const float*)d_in[0];
    const float* key_cache    = (const float*)d_in[1];
    const float* value_cache  = (const float*)d_in[2];
    const int*   block_tables = (const int*)d_in[3];
    const int*   context_lens = (const int*)d_in[4];
    float* out = (float*)d_out;

    float* o_part = (float*)d_ws;
    float* m_part = o_part + O_PART_ELEMS;
    float* l_part = m_part + ML_ELEMS;

    pa_part<<<dim3(NSEQ * KVH * PARTS), dim3(256), 0, stream>>>(
        query, key_cache, value_cache, block_tables, context_lens,
        o_part, m_part, l_part);
    pa_combine<<<dim3(NSEQ * NHEAD), dim3(128), 0, stream>>>(
        o_part, m_part, l_part, context_lens, out);
}